// Round 5
// baseline (950.567 us; speedup 1.0000x reference)
//
#include <hip/hip_runtime.h>
#include <hip/hip_bf16.h>

#define T_DIM 8192
#define H_DIM 2048
#define F_DIM 5632

typedef __attribute__((ext_vector_type(4))) float f32x4;
typedef __attribute__((ext_vector_type(8))) short bf16x8;

static __device__ __forceinline__ void gload16(const void* g, void* l) {
    __builtin_amdgcn_global_load_lds(
        (const __attribute__((address_space(1))) void*)g,
        (__attribute__((address_space(3))) void*)l,
        16, 0, 0);
}

static __device__ __forceinline__ unsigned short f2bf(float f) {
    unsigned int u = __float_as_uint(f);
    u += 0x7fffu + ((u >> 16) & 1u);
    return (unsigned short)(u >> 16);
}

static __device__ __forceinline__ float bf2f(unsigned short u) {
    return __uint_as_float(((unsigned int)u) << 16);
}

// ---- f32 -> bf16 conversion: X ----
__global__ __launch_bounds__(256)
void cvt_x(const float* __restrict__ src, unsigned short* __restrict__ dst, long n)
{
    const long stride = (long)gridDim.x * blockDim.x;
    for (long i = (long)blockIdx.x * blockDim.x + threadIdx.x; i * 4 < n; i += stride) {
        const float4 v = *(const float4*)(src + i * 4);
        ushort4 o;
        o.x = f2bf(v.x); o.y = f2bf(v.y); o.z = f2bf(v.z); o.w = f2bf(v.w);
        *(ushort4*)(dst + i * 4) = o;
    }
}

// ---- f32 -> bf16 conversion: the three expert weight slices ----
__global__ __launch_bounds__(256)
void cvt_w(const float* __restrict__ w1, const float* __restrict__ w2,
           const float* __restrict__ w3, const int* __restrict__ eidx,
           unsigned short* __restrict__ W1b, unsigned short* __restrict__ W2b,
           unsigned short* __restrict__ W3b)
{
    const long seg = (long)F_DIM * H_DIM;
    const long e   = (long)(*eidx);
    const long nchunks = 3 * seg / 4;
    const long stride = (long)gridDim.x * blockDim.x;
    for (long i = (long)blockIdx.x * blockDim.x + threadIdx.x; i < nchunks; i += stride) {
        const long t = i * 4;
        const int  s = (int)(t / seg);
        const long o = t - (long)s * seg;
        const float* src = (s == 0 ? w1 : s == 1 ? w2 : w3) + e * seg + o;
        unsigned short* dst = (s == 0 ? W1b : s == 1 ? W2b : W3b) + o;
        const float4 v = *(const float4*)src;
        ushort4 ov;
        ov.x = f2bf(v.x); ov.y = f2bf(v.y); ov.z = f2bf(v.z); ov.w = f2bf(v.w);
        *(ushort4*)dst = ov;
    }
}

// ---- helpers for the 256x256 / BK=64 8-wave pipelined GEMM ----
static __device__ __forceinline__ void stage_half(const unsigned short* __restrict__ g,
                                                  long grow0, long ldk, long kb,
                                                  unsigned short* l, int t, int i0)
{
    const int r  = t >> 3;
    const int cc = ((t & 7) ^ (r & 7)) << 3;   // inverse-swizzled source column
    #pragma unroll
    for (int i = i0; i < i0 + 2; ++i)
        gload16(g + (grow0 + i * 64 + r) * ldk + kb + cc,
                l + i * 4096 + t * 8);
}

static __device__ __forceinline__ bf16x8 ldsfrag(const unsigned short* base,
                                                 int row, int kk, int q)
{
    return *(const bf16x8*)(base + row * 64 + (((kk * 4 + q) ^ (row & 7)) << 3));
}

#define PHASE_BODY(p, STAGE_STMT)                                              \
    {                                                                          \
        bf16x8 af[2][2];                                                       \
        _Pragma("unroll")                                                      \
        for (int l_ = 0; l_ < 2; ++l_)                                         \
            _Pragma("unroll")                                                  \
            for (int kk = 0; kk < 2; ++kk)                                     \
                af[l_][kk] = ldsfrag(la, wm * 128 + (p) * 32 + l_ * 16 + lr, kk, q); \
        STAGE_STMT;                                                            \
        __builtin_amdgcn_s_barrier();                                          \
        __builtin_amdgcn_s_setprio(1);                                         \
        _Pragma("unroll")                                                      \
        for (int l_ = 0; l_ < 2; ++l_)                                         \
            _Pragma("unroll")                                                  \
            for (int ni = 0; ni < 4; ++ni)                                     \
                _Pragma("unroll")                                              \
                for (int kk = 0; kk < 2; ++kk)                                 \
                    acc[(p) * 2 + l_][ni] = __builtin_amdgcn_mfma_f32_16x16x32_bf16( \
                        af[l_][kk], bf[ni][kk], acc[(p) * 2 + l_][ni], 0, 0, 0);     \
        __builtin_amdgcn_s_setprio(0);                                         \
        __builtin_amdgcn_s_barrier();                                          \
    }

// flat-iteration decode for the persistent fc1 kernel
// f in [0, ntt*64): vt = f>>5 (virtual tile), j = f&31, rt = vt>>1,
// tile' tp = t0p + rt*32, bm = tp/22, bn = tp%22, B = (vt odd) ? W2 : W1.
struct StageP { const unsigned short* B; long arow, brow, kb; };
static __device__ __forceinline__ StageP decode_f(int f, int t0p,
    const unsigned short* W1, const unsigned short* W2)
{
    const int vt = f >> 5, j = f & 31, rt = vt >> 1;
    const int tp = t0p + rt * 32;
    const int bm = tp / 22, bn = tp - bm * 22;
    StageP s;
    s.B    = (vt & 1) ? W2 : W1;
    s.arow = (long)bm * 256;
    s.brow = (long)bn * 256;
    s.kb   = (long)j * 64;
    return s;
}

// ---- persistent fused FC1: per tile, gate pass (X*W1^T) then up pass
// (X*W2^T); gate stashed silu'd/bf16 in a per-block L2-hot blocked slot;
// up epilogue combines and stores H row-major bf16.
__global__ __launch_bounds__(512, 2)
void gemm_fc1(const unsigned short* __restrict__ X,
              const unsigned short* __restrict__ W1,
              const unsigned short* __restrict__ W2,
              unsigned short* __restrict__ Hout,
              unsigned short* Gb)
{
    __shared__ __align__(16) unsigned short sAll[4 * 16384];  // 128 KiB

    const int tid  = threadIdx.x;
    const int lane = tid & 63;
    const int wid  = tid >> 6;
    const int wm   = wid >> 2;
    const int wn   = wid & 3;
    const int q    = lane >> 4;
    const int lr   = lane & 15;

    const int bid  = blockIdx.x;                  // 256 blocks, 1/CU
    const int t0p  = (bid & 7) * 88 + (bid >> 3); // XCD-local tile base
    const int ntt  = (bid < 192) ? 3 : 2;         // tiles this block owns (704 total)
    const int FTOT = ntt * 64;                    // ntt * 2 passes * NK(=32)

    unsigned short* Gslot = Gb + (long)bid * 65536;

    f32x4 acc[8][4] = {};

    // prologue: A(0),B(0) -> buf0 ; B(1) -> buf1
    {
        StageP s0 = decode_f(0, t0p, W1, W2);
        stage_half(X,    s0.arow, H_DIM, 0, sAll,         tid, 0);
        stage_half(X,    s0.arow, H_DIM, 0, sAll,         tid, 2);
        stage_half(s0.B, s0.brow, H_DIM, 0, sAll + 16384, tid, 0);
        stage_half(s0.B, s0.brow, H_DIM, 0, sAll + 16384, tid, 2);
        StageP s1 = decode_f(1, t0p, W1, W2);
        stage_half(s1.B, s1.brow, H_DIM, s1.kb, sAll + 49152, tid, 0);
        stage_half(s1.B, s1.brow, H_DIM, s1.kb, sAll + 49152, tid, 2);
    }

    for (int f = 0; f < FTOT; ++f) {
        unsigned short* la = sAll + (f & 1) * 32768;
        unsigned short* lb = la + 16384;

        if (f + 1 < FTOT) {
            StageP sn = decode_f(f + 1, t0p, W1, W2);
            unsigned short* na = sAll + ((f + 1) & 1) * 32768;
            stage_half(X, sn.arow, H_DIM, sn.kb, na, tid, 0);
            stage_half(X, sn.arow, H_DIM, sn.kb, na, tid, 2);
            asm volatile("s_waitcnt vmcnt(8)" ::: "memory");  // drains A(f),B(f)
        } else {
            asm volatile("s_waitcnt vmcnt(0)" ::: "memory");
        }
        __builtin_amdgcn_s_barrier();

        bf16x8 bf[4][2];
        #pragma unroll
        for (int ni = 0; ni < 4; ++ni)
            #pragma unroll
            for (int kk = 0; kk < 2; ++kk)
                bf[ni][kk] = ldsfrag(lb, wn * 64 + ni * 16 + lr, kk, q);

        PHASE_BODY(0, {})
        PHASE_BODY(1, { if (f + 2 < FTOT) { StageP s2 = decode_f(f + 2, t0p, W1, W2);
                                            stage_half(s2.B, s2.brow, H_DIM, s2.kb, lb, tid, 0); } })
        PHASE_BODY(2, { if (f + 2 < FTOT) { StageP s2 = decode_f(f + 2, t0p, W1, W2);
                                            stage_half(s2.B, s2.brow, H_DIM, s2.kb, lb, tid, 2); } })
        PHASE_BODY(3, {})

        const int fm = f & 63;
        if (fm == 31) {
            // gate pass done: silu -> bf16 -> blocked per-block slot (L2-hot)
            #pragma unroll
            for (int mi = 0; mi < 8; ++mi)
                #pragma unroll
                for (int ni = 0; ni < 4; ++ni) {
                    ushort4 o;
                    #pragma unroll
                    for (int r = 0; r < 4; ++r) {
                        const float g = acc[mi][ni][r];
                        const float s = __fdividef(g, 1.0f + __expf(-g));
                        (&o.x)[r] = f2bf(s);
                    }
                    *(ushort4*)(Gslot + (mi * 4 + ni) * 2048 + tid * 4) = o;
                    acc[mi][ni] = (f32x4){0.f, 0.f, 0.f, 0.f};
                }
        } else if (fm == 63) {
            // up pass done: combine with stashed silu(gate), store H row-major
            const int rt = f >> 6;
            const int tp = t0p + rt * 32;
            const int bm = tp / 22, bn = tp - bm * 22;
            const long orow = (long)bm * 256 + wm * 128;
            const long ocol = (long)bn * 256 + wn * 64;
            #pragma unroll
            for (int mi = 0; mi < 8; ++mi) {
                ushort4 sg[4];
                #pragma unroll
                for (int ni = 0; ni < 4; ++ni)
                    sg[ni] = *(const ushort4*)(Gslot + (mi * 4 + ni) * 2048 + tid * 4);
                #pragma unroll
                for (int ni = 0; ni < 4; ++ni) {
                    #pragma unroll
                    for (int r = 0; r < 4; ++r) {
                        const float h = bf2f((&sg[ni].x)[r]) * acc[mi][ni][r];
                        Hout[(orow + mi * 16 + q * 4 + r) * (long)F_DIM +
                             (ocol + ni * 16 + lr)] = f2bf(h);
                    }
                    acc[mi][ni] = (f32x4){0.f, 0.f, 0.f, 0.f};
                }
            }
        }
    }
}

// ---- GEMM2: Out = H * W3^T.  H [T,F] bf16, W3 [H,F] bf16, Out [T,H] f32 ----
__global__ __launch_bounds__(512, 2)
void gemm_out(const unsigned short* __restrict__ A,
              const unsigned short* __restrict__ B,
              float* __restrict__ Out)
{
    constexpr int NK  = F_DIM / 64;   // 88
    constexpr int NBN = H_DIM / 256;  // 8

    __shared__ __align__(16) unsigned short sAll[4 * 16384];

    const int tid  = threadIdx.x;
    const int lane = tid & 63;
    const int wid  = tid >> 6;
    const int wm   = wid >> 2;
    const int wn   = wid & 3;
    const int q    = lane >> 4;
    const int lr   = lane & 15;

    const int nwg = gridDim.x;                 // 256
    const int bid = blockIdx.x;
    const int cpx = nwg >> 3;
    const int swz = (bid & 7) * cpx + (bid >> 3);
    const int bm  = swz / NBN;
    const int bn  = swz % NBN;

    const long arow0 = (long)bm * 256;
    const long brow0 = (long)bn * 256;

    f32x4 acc[8][4] = {};

    stage_half(A, arow0, F_DIM, 0,  sAll,          tid, 0);
    stage_half(A, arow0, F_DIM, 0,  sAll,          tid, 2);
    stage_half(B, brow0, F_DIM, 0,  sAll + 16384,  tid, 0);
    stage_half(B, brow0, F_DIM, 0,  sAll + 16384,  tid, 2);
    stage_half(B, brow0, F_DIM, 64, sAll + 49152,  tid, 0);
    stage_half(B, brow0, F_DIM, 64, sAll + 49152,  tid, 2);

    for (int j = 0; j < NK; ++j) {
        unsigned short* la = sAll + (j & 1) * 32768;
        unsigned short* lb = la + 16384;

        if (j + 1 < NK) {
            unsigned short* na = sAll + ((j + 1) & 1) * 32768;
            stage_half(A, arow0, F_DIM, (long)(j + 1) * 64, na, tid, 0);
            stage_half(A, arow0, F_DIM, (long)(j + 1) * 64, na, tid, 2);
            asm volatile("s_waitcnt vmcnt(8)" ::: "memory");
        } else {
            asm volatile("s_waitcnt vmcnt(0)" ::: "memory");
        }
        __builtin_amdgcn_s_barrier();

        bf16x8 bf[4][2];
        #pragma unroll
        for (int ni = 0; ni < 4; ++ni)
            #pragma unroll
            for (int kk = 0; kk < 2; ++kk)
                bf[ni][kk] = ldsfrag(lb, wn * 64 + ni * 16 + lr, kk, q);

        PHASE_BODY(0, {})
        PHASE_BODY(1, { if (j + 2 < NK) stage_half(B, brow0, F_DIM, (long)(j + 2) * 64, lb, tid, 0); })
        PHASE_BODY(2, { if (j + 2 < NK) stage_half(B, brow0, F_DIM, (long)(j + 2) * 64, lb, tid, 2); })
        PHASE_BODY(3, {})
    }

    const long orow = (long)bm * 256 + wm * 128;
    const long ocol = (long)bn * 256 + wn * 64;
    #pragma unroll
    for (int mi = 0; mi < 8; ++mi)
        #pragma unroll
        for (int ni = 0; ni < 4; ++ni)
            #pragma unroll
            for (int r = 0; r < 4; ++r)
                Out[(orow + mi * 16 + q * 4 + r) * (long)H_DIM + (ocol + ni * 16 + lr)]
                    = acc[mi][ni][r];
}

extern "C" void kernel_launch(void* const* d_in, const int* in_sizes, int n_in,
                              void* d_out, int out_size, void* d_ws, size_t ws_size,
                              hipStream_t stream)
{
    const int*   eidx = (const int*)d_in[0];
    const float* x    = (const float*)d_in[1];
    const float* w1   = (const float*)d_in[2];
    const float* w2   = (const float*)d_in[3];
    const float* w3   = (const float*)d_in[4];
    float* out = (float*)d_out;

    const size_t SZ_X = (size_t)T_DIM * H_DIM;
    const size_t SZ_W = (size_t)F_DIM * H_DIM;
    const size_t SZ_H = (size_t)T_DIM * F_DIM;

    unsigned short* Xb  = (unsigned short*)d_ws;
    unsigned short* W1b = Xb  + SZ_X;
    unsigned short* W2b = W1b + SZ_W;
    unsigned short* W3b = W2b + SZ_W;
    unsigned short* Hb  = W3b + SZ_W;
    unsigned short* Gb  = Hb  + SZ_H;      // 256 * 65536 elems (33.5 MB)

    cvt_x<<<2048, 256, 0, stream>>>(x, Xb, (long)SZ_X);
    cvt_w<<<2048, 256, 0, stream>>>(w1, w2, w3, eidx, W1b, W2b, W3b);

    gemm_fc1<<<256, 512, 0, stream>>>(Xb, W1b, W2b, Hb, Gb);
    gemm_out<<<256, 512, 0, stream>>>(Hb, W3b, out);
}

// Round 6
// 582.693 us; speedup vs baseline: 1.6313x; 1.6313x over previous
//
#include <hip/hip_runtime.h>
#include <hip/hip_bf16.h>

#define T_DIM 8192
#define H_DIM 2048
#define F_DIM 5632

typedef __attribute__((ext_vector_type(4))) float f32x4;
typedef __attribute__((ext_vector_type(8))) short bf16x8;

static __device__ __forceinline__ void gload16(const void* g, void* l) {
    __builtin_amdgcn_global_load_lds(
        (const __attribute__((address_space(1))) void*)g,
        (__attribute__((address_space(3))) void*)l,
        16, 0, 0);
}

static __device__ __forceinline__ unsigned short f2bf(float f) {
    unsigned int u = __float_as_uint(f);
    u += 0x7fffu + ((u >> 16) & 1u);
    return (unsigned short)(u >> 16);
}

// ---- f32 -> bf16 conversion: X ----
__global__ __launch_bounds__(256)
void cvt_x(const float* __restrict__ src, unsigned short* __restrict__ dst, long n)
{
    const long stride = (long)gridDim.x * blockDim.x;
    for (long i = (long)blockIdx.x * blockDim.x + threadIdx.x; i * 4 < n; i += stride) {
        const float4 v = *(const float4*)(src + i * 4);
        ushort4 o;
        o.x = f2bf(v.x); o.y = f2bf(v.y); o.z = f2bf(v.z); o.w = f2bf(v.w);
        *(ushort4*)(dst + i * 4) = o;
    }
}

// ---- f32 -> bf16 conversion: the three expert weight slices ----
__global__ __launch_bounds__(256)
void cvt_w(const float* __restrict__ w1, const float* __restrict__ w2,
           const float* __restrict__ w3, const int* __restrict__ eidx,
           unsigned short* __restrict__ W1b, unsigned short* __restrict__ W2b,
           unsigned short* __restrict__ W3b)
{
    const long seg = (long)F_DIM * H_DIM;
    const long e   = (long)(*eidx);
    const long nchunks = 3 * seg / 4;
    const long stride = (long)gridDim.x * blockDim.x;
    for (long i = (long)blockIdx.x * blockDim.x + threadIdx.x; i < nchunks; i += stride) {
        const long t = i * 4;
        const int  s = (int)(t / seg);
        const long o = t - (long)s * seg;
        const float* src = (s == 0 ? w1 : s == 1 ? w2 : w3) + e * seg + o;
        unsigned short* dst = (s == 0 ? W1b : s == 1 ? W2b : W3b) + o;
        const float4 v = *(const float4*)src;
        ushort4 ov;
        ov.x = f2bf(v.x); ov.y = f2bf(v.y); ov.z = f2bf(v.z); ov.w = f2bf(v.w);
        *(ushort4*)dst = ov;
    }
}

// ---- helpers for the 256-row / BK=64 8-wave pipelined GEMM ----
// One call stages 128 rows (quarters i0, i0+1). LDS dest lane-linear;
// global source column inverse-XOR-swizzled (rule #21).
static __device__ __forceinline__ void stage_half(const unsigned short* __restrict__ g,
                                                  long grow0, long ldk, long kb,
                                                  unsigned short* l, int t, int i0)
{
    const int r  = t >> 3;
    const int cc = ((t & 7) ^ (r & 7)) << 3;
    #pragma unroll
    for (int i = i0; i < i0 + 2; ++i)
        gload16(g + (grow0 + i * 64 + r) * ldk + kb + cc,
                l + i * 4096 + t * 8);
}

// fc1 B-tile staging: 256 logical rows interleave W1/W2 at 32-row granularity:
// row br: g2=br>>6 (wave group), rr=br&63; rr<32 -> W1[bn*128+g2*32+rr],
// else W2[bn*128+g2*32+rr-32]. Source select is wave-uniform (8-row spans).
static __device__ __forceinline__ void stage_fc1B(const unsigned short* __restrict__ W1,
                                                  const unsigned short* __restrict__ W2,
                                                  long bn128, long kb,
                                                  unsigned short* l, int t, int i0)
{
    const int r  = t >> 3;
    const int cc = ((t & 7) ^ (r & 7)) << 3;
    #pragma unroll
    for (int i = i0; i < i0 + 2; ++i) {
        const int br = i * 64 + r;
        const int g2 = br >> 6;
        const int rr = br & 63;
        const unsigned short* src = (rr < 32) ? W1 : W2;
        const long row = bn128 + g2 * 32 + (rr & 31);
        gload16(src + row * H_DIM + kb + cc, l + i * 4096 + t * 8);
    }
}

static __device__ __forceinline__ bf16x8 ldsfrag(const unsigned short* base,
                                                 int row, int kk, int q)
{
    return *(const bf16x8*)(base + row * 64 + (((kk * 4 + q) ^ (row & 7)) << 3));
}

#define PHASE_BODY(p, STAGE_STMT)                                              \
    {                                                                          \
        bf16x8 af[2][2];                                                       \
        _Pragma("unroll")                                                      \
        for (int l_ = 0; l_ < 2; ++l_)                                         \
            _Pragma("unroll")                                                  \
            for (int kk = 0; kk < 2; ++kk)                                     \
                af[l_][kk] = ldsfrag(la, wm * 128 + (p) * 32 + l_ * 16 + lr, kk, q); \
        STAGE_STMT;                                                            \
        __builtin_amdgcn_s_barrier();                                          \
        __builtin_amdgcn_s_setprio(1);                                         \
        _Pragma("unroll")                                                      \
        for (int l_ = 0; l_ < 2; ++l_)                                         \
            _Pragma("unroll")                                                  \
            for (int ni = 0; ni < 4; ++ni)                                     \
                _Pragma("unroll")                                              \
                for (int kk = 0; kk < 2; ++kk)                                 \
                    acc[(p) * 2 + l_][ni] = __builtin_amdgcn_mfma_f32_16x16x32_bf16( \
                        af[l_][kk], bf[ni][kk], acc[(p) * 2 + l_][ni], 0, 0, 0);     \
        __builtin_amdgcn_s_setprio(0);                                         \
        __builtin_amdgcn_s_barrier();                                          \
    }

// flat-iteration decode: vt = t0 + (f>>5), bn = vt>>2, bm = x*4 + (vt&3)
struct FD { long arow, bn128, kb; };
static __device__ __forceinline__ FD fdec(int f, int t0, int x)
{
    const int vt = t0 + (f >> 5);
    FD d;
    d.bn128 = (long)(vt >> 2) * 128;
    d.arow  = (long)(x * 4 + (vt & 3)) * 256;
    d.kb    = (long)(f & 31) * 64;
    return d;
}

// ---- persistent fused FC1: per virtual tile (256 X-rows x 128 F-cols),
// gate AND up computed simultaneously in registers (W1/W2 interleaved B-tile);
// epilogue: h = silu(g)*u in-register -> bf16 row-major H. No gate memory.
__global__ __launch_bounds__(512, 2)
void gemm_fc1(const unsigned short* __restrict__ X,
              const unsigned short* __restrict__ W1,
              const unsigned short* __restrict__ W2,
              unsigned short* __restrict__ Hout)
{
    __shared__ __align__(16) unsigned short sAll[4 * 16384];  // 128 KiB

    const int tid  = threadIdx.x;
    const int lane = tid & 63;
    const int wid  = tid >> 6;
    const int wm   = wid >> 2;
    const int wn   = wid & 3;
    const int q    = lane >> 4;
    const int lr   = lane & 15;

    const int bid = blockIdx.x;        // 256 blocks, 1/CU
    const int x   = bid & 7;           // XCD (locality heuristic only)
    const int y   = bid >> 3;          // 0..31
    const int ntt = (y < 16) ? 6 : 5;  // 176 tiles per XCD, 1408 total
    const int t0  = (y < 16) ? 6 * y : 5 * y + 16;
    const int FTOT = ntt * 32;

    f32x4 acc[8][4] = {};

    // prologue: A(0),B(0) -> buf0 ; B(1) -> buf1
    {
        FD d0 = fdec(0, t0, x);
        stage_half(X, d0.arow, H_DIM, d0.kb, sAll, tid, 0);
        stage_half(X, d0.arow, H_DIM, d0.kb, sAll, tid, 2);
        stage_fc1B(W1, W2, d0.bn128, d0.kb, sAll + 16384, tid, 0);
        stage_fc1B(W1, W2, d0.bn128, d0.kb, sAll + 16384, tid, 2);
        FD d1 = fdec(1, t0, x);
        stage_fc1B(W1, W2, d1.bn128, d1.kb, sAll + 49152, tid, 0);
        stage_fc1B(W1, W2, d1.bn128, d1.kb, sAll + 49152, tid, 2);
    }

    for (int f = 0; f < FTOT; ++f) {
        unsigned short* la = sAll + (f & 1) * 32768;
        unsigned short* lb = la + 16384;

        if (f + 1 < FTOT) {
            FD dn = fdec(f + 1, t0, x);
            unsigned short* na = sAll + ((f + 1) & 1) * 32768;
            stage_half(X, dn.arow, H_DIM, dn.kb, na, tid, 0);
            stage_half(X, dn.arow, H_DIM, dn.kb, na, tid, 2);
            asm volatile("s_waitcnt vmcnt(8)" ::: "memory");  // A(f),B(f) drained
        } else {
            asm volatile("s_waitcnt vmcnt(0)" ::: "memory");
        }
        __builtin_amdgcn_s_barrier();

        bf16x8 bf[4][2];
        #pragma unroll
        for (int ni = 0; ni < 4; ++ni)
            #pragma unroll
            for (int kk = 0; kk < 2; ++kk)
                bf[ni][kk] = ldsfrag(lb, wn * 64 + ni * 16 + lr, kk, q);

        PHASE_BODY(0, {})
        PHASE_BODY(1, { if (f + 2 < FTOT) { FD d2 = fdec(f + 2, t0, x);
                                            stage_fc1B(W1, W2, d2.bn128, d2.kb, lb, tid, 0); } })
        PHASE_BODY(2, { if (f + 2 < FTOT) { FD d2 = fdec(f + 2, t0, x);
                                            stage_fc1B(W1, W2, d2.bn128, d2.kb, lb, tid, 2); } })
        PHASE_BODY(3, {})

        if ((f & 31) == 31) {
            // tile done: acc[mi][0..1]=gate, acc[mi][2..3]=up, same cols
            const int vt = t0 + (f >> 5);
            const int bn = vt >> 2;
            const int bm = x * 4 + (vt & 3);
            const long orow = (long)bm * 256 + wm * 128;
            const long ocol = (long)bn * 128 + wn * 32;
            #pragma unroll
            for (int mi = 0; mi < 8; ++mi) {
                #pragma unroll
                for (int nj = 0; nj < 2; ++nj)
                    #pragma unroll
                    for (int r = 0; r < 4; ++r) {
                        const float g = acc[mi][nj][r];
                        const float u = acc[mi][nj + 2][r];
                        const float h = __fdividef(g, 1.0f + __expf(-g)) * u;
                        Hout[(orow + mi * 16 + q * 4 + r) * (long)F_DIM +
                             (ocol + nj * 16 + lr)] = f2bf(h);
                    }
                #pragma unroll
                for (int ni = 0; ni < 4; ++ni)
                    acc[mi][ni] = (f32x4){0.f, 0.f, 0.f, 0.f};
            }
        }
    }
}

// ---- GEMM2: Out = H * W3^T.  H [T,F] bf16, W3 [H,F] bf16, Out [T,H] f32 ----
__global__ __launch_bounds__(512, 2)
void gemm_out(const unsigned short* __restrict__ A,
              const unsigned short* __restrict__ B,
              float* __restrict__ Out)
{
    constexpr int NK  = F_DIM / 64;   // 88
    constexpr int NBN = H_DIM / 256;  // 8

    __shared__ __align__(16) unsigned short sAll[4 * 16384];

    const int tid  = threadIdx.x;
    const int lane = tid & 63;
    const int wid  = tid >> 6;
    const int wm   = wid >> 2;
    const int wn   = wid & 3;
    const int q    = lane >> 4;
    const int lr   = lane & 15;

    const int nwg = gridDim.x;                 // 256
    const int bid = blockIdx.x;
    const int cpx = nwg >> 3;
    const int swz = (bid & 7) * cpx + (bid >> 3);
    const int bm  = swz / NBN;
    const int bn  = swz % NBN;

    const long arow0 = (long)bm * 256;
    const long brow0 = (long)bn * 256;

    f32x4 acc[8][4] = {};

    stage_half(A, arow0, F_DIM, 0,  sAll,          tid, 0);
    stage_half(A, arow0, F_DIM, 0,  sAll,          tid, 2);
    stage_half(B, brow0, F_DIM, 0,  sAll + 16384,  tid, 0);
    stage_half(B, brow0, F_DIM, 0,  sAll + 16384,  tid, 2);
    stage_half(B, brow0, F_DIM, 64, sAll + 49152,  tid, 0);
    stage_half(B, brow0, F_DIM, 64, sAll + 49152,  tid, 2);

    for (int j = 0; j < NK; ++j) {
        unsigned short* la = sAll + (j & 1) * 32768;
        unsigned short* lb = la + 16384;

        if (j + 1 < NK) {
            unsigned short* na = sAll + ((j + 1) & 1) * 32768;
            stage_half(A, arow0, F_DIM, (long)(j + 1) * 64, na, tid, 0);
            stage_half(A, arow0, F_DIM, (long)(j + 1) * 64, na, tid, 2);
            asm volatile("s_waitcnt vmcnt(8)" ::: "memory");
        } else {
            asm volatile("s_waitcnt vmcnt(0)" ::: "memory");
        }
        __builtin_amdgcn_s_barrier();

        bf16x8 bf[4][2];
        #pragma unroll
        for (int ni = 0; ni < 4; ++ni)
            #pragma unroll
            for (int kk = 0; kk < 2; ++kk)
                bf[ni][kk] = ldsfrag(lb, wn * 64 + ni * 16 + lr, kk, q);

        PHASE_BODY(0, {})
        PHASE_BODY(1, { if (j + 2 < NK) stage_half(B, brow0, F_DIM, (long)(j + 2) * 64, lb, tid, 0); })
        PHASE_BODY(2, { if (j + 2 < NK) stage_half(B, brow0, F_DIM, (long)(j + 2) * 64, lb, tid, 2); })
        PHASE_BODY(3, {})
    }

    const long orow = (long)bm * 256 + wm * 128;
    const long ocol = (long)bn * 256 + wn * 64;
    #pragma unroll
    for (int mi = 0; mi < 8; ++mi)
        #pragma unroll
        for (int ni = 0; ni < 4; ++ni)
            #pragma unroll
            for (int r = 0; r < 4; ++r)
                Out[(orow + mi * 16 + q * 4 + r) * (long)H_DIM + (ocol + ni * 16 + lr)]
                    = acc[mi][ni][r];
}

extern "C" void kernel_launch(void* const* d_in, const int* in_sizes, int n_in,
                              void* d_out, int out_size, void* d_ws, size_t ws_size,
                              hipStream_t stream)
{
    const int*   eidx = (const int*)d_in[0];
    const float* x    = (const float*)d_in[1];
    const float* w1   = (const float*)d_in[2];
    const float* w2   = (const float*)d_in[3];
    const float* w3   = (const float*)d_in[4];
    float* out = (float*)d_out;

    const size_t SZ_X = (size_t)T_DIM * H_DIM;
    const size_t SZ_W = (size_t)F_DIM * H_DIM;

    unsigned short* Xb  = (unsigned short*)d_ws;
    unsigned short* W1b = Xb  + SZ_X;
    unsigned short* W2b = W1b + SZ_W;
    unsigned short* W3b = W2b + SZ_W;
    unsigned short* Hb  = W3b + SZ_W;

    cvt_x<<<2048, 256, 0, stream>>>(x, Xb, (long)SZ_X);
    cvt_w<<<2048, 256, 0, stream>>>(w1, w2, w3, eidx, W1b, W2b, W3b);

    gemm_fc1<<<256, 512, 0, stream>>>(Xb, W1b, W2b, Hb);
    gemm_out<<<256, 512, 0, stream>>>(Hb, W3b, out);
}

// Round 7
// 551.783 us; speedup vs baseline: 1.7227x; 1.0560x over previous
//
#include <hip/hip_runtime.h>
#include <hip/hip_bf16.h>

#define T_DIM 8192
#define H_DIM 2048
#define F_DIM 5632

typedef __attribute__((ext_vector_type(4))) float f32x4;
typedef __attribute__((ext_vector_type(8))) short bf16x8;

static __device__ __forceinline__ void gload16(const void* g, void* l) {
    __builtin_amdgcn_global_load_lds(
        (const __attribute__((address_space(1))) void*)g,
        (__attribute__((address_space(3))) void*)l,
        16, 0, 0);
}

static __device__ __forceinline__ unsigned short f2bf(float f) {
    unsigned int u = __float_as_uint(f);
    u += 0x7fffu + ((u >> 16) & 1u);
    return (unsigned short)(u >> 16);
}

// ---- f32 -> bf16 conversion: X ----
__global__ __launch_bounds__(256)
void cvt_x(const float* __restrict__ src, unsigned short* __restrict__ dst, long n)
{
    const long stride = (long)gridDim.x * blockDim.x;
    for (long i = (long)blockIdx.x * blockDim.x + threadIdx.x; i * 4 < n; i += stride) {
        const float4 v = *(const float4*)(src + i * 4);
        ushort4 o;
        o.x = f2bf(v.x); o.y = f2bf(v.y); o.z = f2bf(v.z); o.w = f2bf(v.w);
        *(ushort4*)(dst + i * 4) = o;
    }
}

// ---- f32 -> bf16 weight conversion.
// W1/W2 are written INTERLEAVED into W12[11264 x 2048]:
//   W1 row r -> R = (r>>7)*256 + ((r&127)>>5)*64 + (r&31)
//   W2 row r -> R = same + 32
// (exactly the round-6 verified stage_fc1B mapping, moved to the cvt pass).
// W3 is converted linearly.
__global__ __launch_bounds__(256)
void cvt_w(const float* __restrict__ w1, const float* __restrict__ w2,
           const float* __restrict__ w3, const int* __restrict__ eidx,
           unsigned short* __restrict__ W12, unsigned short* __restrict__ W3b)
{
    const long seg = (long)F_DIM * H_DIM;
    const long e   = (long)(*eidx);
    const long nchunks = 3 * seg / 4;
    const long stride = (long)gridDim.x * blockDim.x;
    for (long i = (long)blockIdx.x * blockDim.x + threadIdx.x; i < nchunks; i += stride) {
        const long t = i * 4;
        const int  s = (int)(t / seg);
        const long o = t - (long)s * seg;
        const float4 v = *(const float4*)((s == 0 ? w1 : s == 1 ? w2 : w3) + e * seg + o);
        ushort4 ov;
        ov.x = f2bf(v.x); ov.y = f2bf(v.y); ov.z = f2bf(v.z); ov.w = f2bf(v.w);
        if (s == 2) {
            *(ushort4*)(W3b + o) = ov;
        } else {
            const long r   = o >> 11;           // source row (H_DIM = 2048)
            const long col = o & 2047;
            const int  l7  = (int)(r & 127);
            const long R   = (r >> 7) * 256 + (l7 >> 5) * 64 + (l7 & 31)
                           + (s == 1 ? 32 : 0);
            *(ushort4*)(W12 + R * 2048 + col) = ov;
        }
    }
}

// ---- helpers for the 256-row / BK=64 8-wave pipelined GEMM ----
// One call stages 128 rows (quarters i0, i0+1). LDS dest lane-linear;
// global source column inverse-XOR-swizzled (rule #21).
static __device__ __forceinline__ void stage_half(const unsigned short* __restrict__ g,
                                                  long grow0, long ldk, long kb,
                                                  unsigned short* l, int t, int i0)
{
    const int r  = t >> 3;
    const int cc = ((t & 7) ^ (r & 7)) << 3;
    #pragma unroll
    for (int i = i0; i < i0 + 2; ++i)
        gload16(g + (grow0 + i * 64 + r) * ldk + kb + cc,
                l + i * 4096 + t * 8);
}

static __device__ __forceinline__ bf16x8 ldsfrag(const unsigned short* base,
                                                 int row, int kk, int q)
{
    return *(const bf16x8*)(base + row * 64 + (((kk * 4 + q) ^ (row & 7)) << 3));
}

#define PHASE_BODY(p, STAGE_STMT)                                              \
    {                                                                          \
        bf16x8 af[2][2];                                                       \
        _Pragma("unroll")                                                      \
        for (int l_ = 0; l_ < 2; ++l_)                                         \
            _Pragma("unroll")                                                  \
            for (int kk = 0; kk < 2; ++kk)                                     \
                af[l_][kk] = ldsfrag(la, wm * 128 + (p) * 32 + l_ * 16 + lr, kk, q); \
        STAGE_STMT;                                                            \
        __builtin_amdgcn_s_barrier();                                          \
        __builtin_amdgcn_s_setprio(1);                                         \
        _Pragma("unroll")                                                      \
        for (int l_ = 0; l_ < 2; ++l_)                                         \
            _Pragma("unroll")                                                  \
            for (int ni = 0; ni < 4; ++ni)                                     \
                _Pragma("unroll")                                              \
                for (int kk = 0; kk < 2; ++kk)                                 \
                    acc[(p) * 2 + l_][ni] = __builtin_amdgcn_mfma_f32_16x16x32_bf16( \
                        af[l_][kk], bf[ni][kk], acc[(p) * 2 + l_][ni], 0, 0, 0);     \
        __builtin_amdgcn_s_setprio(0);                                         \
        __builtin_amdgcn_s_barrier();                                          \
    }

// ---- FC1: one 256x(128 gate + 128 up) tile per block, K = 2048.
// B = interleaved W12; acc[mi][0..1] = gate, acc[mi][2..3] = up for the SAME
// output columns in the same wave; terminal epilogue h = silu(g)*u.
__global__ __launch_bounds__(512, 2)
void gemm_fc1(const unsigned short* __restrict__ X,
              const unsigned short* __restrict__ W12,
              unsigned short* __restrict__ Hout)
{
    constexpr int NK = H_DIM / 64;   // 32

    __shared__ __align__(16) unsigned short sAll[4 * 16384];  // 128 KiB

    const int tid  = threadIdx.x;
    const int lane = tid & 63;
    const int wid  = tid >> 6;
    const int wm   = wid >> 2;
    const int wn   = wid & 3;
    const int q    = lane >> 4;
    const int lr   = lane & 15;

    // grid 1408: XCD x owns 176 consecutive tiles; bm-fast within bn-quads
    // -> concurrent blocks share W panels 4-way + keep 4 X panels L2-hot.
    const int bid = blockIdx.x;
    const int x   = bid & 7;
    const int i   = bid >> 3;        // 0..175
    const int bn  = i >> 2;          // 0..43
    const int bm  = x * 4 + (i & 3); // 0..31

    const long arow0 = (long)bm * 256;
    const long brow0 = (long)bn * 256;

    f32x4 acc[8][4] = {};

    stage_half(X,   arow0, H_DIM, 0,  sAll,          tid, 0);
    stage_half(X,   arow0, H_DIM, 0,  sAll,          tid, 2);
    stage_half(W12, brow0, H_DIM, 0,  sAll + 16384,  tid, 0);
    stage_half(W12, brow0, H_DIM, 0,  sAll + 16384,  tid, 2);
    stage_half(W12, brow0, H_DIM, 64, sAll + 49152,  tid, 0);
    stage_half(W12, brow0, H_DIM, 64, sAll + 49152,  tid, 2);

    for (int j = 0; j < NK; ++j) {
        unsigned short* la = sAll + (j & 1) * 32768;
        unsigned short* lb = la + 16384;

        if (j + 1 < NK) {
            unsigned short* na = sAll + ((j + 1) & 1) * 32768;
            stage_half(X, arow0, H_DIM, (long)(j + 1) * 64, na, tid, 0);
            stage_half(X, arow0, H_DIM, (long)(j + 1) * 64, na, tid, 2);
            asm volatile("s_waitcnt vmcnt(8)" ::: "memory");  // tile j drained
        } else {
            asm volatile("s_waitcnt vmcnt(0)" ::: "memory");
        }
        __builtin_amdgcn_s_barrier();

        bf16x8 bf[4][2];
        #pragma unroll
        for (int ni = 0; ni < 4; ++ni)
            #pragma unroll
            for (int kk = 0; kk < 2; ++kk)
                bf[ni][kk] = ldsfrag(lb, wn * 64 + ni * 16 + lr, kk, q);

        PHASE_BODY(0, {})
        PHASE_BODY(1, { if (j + 2 < NK) stage_half(W12, brow0, H_DIM, (long)(j + 2) * 64, lb, tid, 0); })
        PHASE_BODY(2, { if (j + 2 < NK) stage_half(W12, brow0, H_DIM, (long)(j + 2) * 64, lb, tid, 2); })
        PHASE_BODY(3, {})
    }

    // terminal epilogue: silu(gate)*up in registers -> bf16 H
    const long orow = (long)bm * 256 + wm * 128;
    const long ocol = (long)bn * 128 + wn * 32;
    #pragma unroll
    for (int mi = 0; mi < 8; ++mi)
        #pragma unroll
        for (int nj = 0; nj < 2; ++nj)
            #pragma unroll
            for (int r = 0; r < 4; ++r) {
                const float g = acc[mi][nj][r];
                const float u = acc[mi][nj + 2][r];
                const float h = __fdividef(g, 1.0f + __expf(-g)) * u;
                Hout[(orow + mi * 16 + q * 4 + r) * (long)F_DIM +
                     (ocol + nj * 16 + lr)] = f2bf(h);
            }
}

// ---- GEMM2: Out = H * W3^T.  H [T,F] bf16, W3 [H,F] bf16, Out [T,H] f32 ----
__global__ __launch_bounds__(512, 2)
void gemm_out(const unsigned short* __restrict__ A,
              const unsigned short* __restrict__ B,
              float* __restrict__ Out)
{
    constexpr int NK  = F_DIM / 64;   // 88
    constexpr int NBN = H_DIM / 256;  // 8

    __shared__ __align__(16) unsigned short sAll[4 * 16384];

    const int tid  = threadIdx.x;
    const int lane = tid & 63;
    const int wid  = tid >> 6;
    const int wm   = wid >> 2;
    const int wn   = wid & 3;
    const int q    = lane >> 4;
    const int lr   = lane & 15;

    const int nwg = gridDim.x;                 // 256
    const int bid = blockIdx.x;
    const int cpx = nwg >> 3;
    const int swz = (bid & 7) * cpx + (bid >> 3);
    const int bm  = swz / NBN;
    const int bn  = swz % NBN;

    const long arow0 = (long)bm * 256;
    const long brow0 = (long)bn * 256;

    f32x4 acc[8][4] = {};

    stage_half(A, arow0, F_DIM, 0,  sAll,          tid, 0);
    stage_half(A, arow0, F_DIM, 0,  sAll,          tid, 2);
    stage_half(B, brow0, F_DIM, 0,  sAll + 16384,  tid, 0);
    stage_half(B, brow0, F_DIM, 0,  sAll + 16384,  tid, 2);
    stage_half(B, brow0, F_DIM, 64, sAll + 49152,  tid, 0);
    stage_half(B, brow0, F_DIM, 64, sAll + 49152,  tid, 2);

    for (int j = 0; j < NK; ++j) {
        unsigned short* la = sAll + (j & 1) * 32768;
        unsigned short* lb = la + 16384;

        if (j + 1 < NK) {
            unsigned short* na = sAll + ((j + 1) & 1) * 32768;
            stage_half(A, arow0, F_DIM, (long)(j + 1) * 64, na, tid, 0);
            stage_half(A, arow0, F_DIM, (long)(j + 1) * 64, na, tid, 2);
            asm volatile("s_waitcnt vmcnt(8)" ::: "memory");
        } else {
            asm volatile("s_waitcnt vmcnt(0)" ::: "memory");
        }
        __builtin_amdgcn_s_barrier();

        bf16x8 bf[4][2];
        #pragma unroll
        for (int ni = 0; ni < 4; ++ni)
            #pragma unroll
            for (int kk = 0; kk < 2; ++kk)
                bf[ni][kk] = ldsfrag(lb, wn * 64 + ni * 16 + lr, kk, q);

        PHASE_BODY(0, {})
        PHASE_BODY(1, { if (j + 2 < NK) stage_half(B, brow0, F_DIM, (long)(j + 2) * 64, lb, tid, 0); })
        PHASE_BODY(2, { if (j + 2 < NK) stage_half(B, brow0, F_DIM, (long)(j + 2) * 64, lb, tid, 2); })
        PHASE_BODY(3, {})
    }

    const long orow = (long)bm * 256 + wm * 128;
    const long ocol = (long)bn * 256 + wn * 64;
    #pragma unroll
    for (int mi = 0; mi < 8; ++mi)
        #pragma unroll
        for (int ni = 0; ni < 4; ++ni)
            #pragma unroll
            for (int r = 0; r < 4; ++r)
                Out[(orow + mi * 16 + q * 4 + r) * (long)H_DIM + (ocol + ni * 16 + lr)]
                    = acc[mi][ni][r];
}

extern "C" void kernel_launch(void* const* d_in, const int* in_sizes, int n_in,
                              void* d_out, int out_size, void* d_ws, size_t ws_size,
                              hipStream_t stream)
{
    const int*   eidx = (const int*)d_in[0];
    const float* x    = (const float*)d_in[1];
    const float* w1   = (const float*)d_in[2];
    const float* w2   = (const float*)d_in[3];
    const float* w3   = (const float*)d_in[4];
    float* out = (float*)d_out;

    const size_t SZ_X = (size_t)T_DIM * H_DIM;
    const size_t SZ_W = (size_t)F_DIM * H_DIM;

    unsigned short* Xb  = (unsigned short*)d_ws;
    unsigned short* W12 = Xb  + SZ_X;            // [11264 x 2048] interleaved
    unsigned short* W3b = W12 + 2 * SZ_W;
    unsigned short* Hb  = W3b + SZ_W;

    cvt_x<<<2048, 256, 0, stream>>>(x, Xb, (long)SZ_X);
    cvt_w<<<2048, 256, 0, stream>>>(w1, w2, w3, eidx, W12, W3b);

    gemm_fc1<<<(T_DIM / 256) * (F_DIM / 128), 512, 0, stream>>>(Xb, W12, Hb);
    gemm_out<<<(T_DIM / 256) * (H_DIM / 256), 512, 0, stream>>>(Hb, W3b, out);
}

// Round 8
// 550.767 us; speedup vs baseline: 1.7259x; 1.0018x over previous
//
#include <hip/hip_runtime.h>
#include <hip/hip_bf16.h>

#define T_DIM 8192
#define H_DIM 2048
#define F_DIM 5632
#define PLD   2112   // padded row stride (elems) for K=2048 operands: 4224 B,
                     // breaks 4 KB power-of-2 HBM-channel / set aliasing

typedef __attribute__((ext_vector_type(4))) float f32x4;
typedef __attribute__((ext_vector_type(8))) short bf16x8;

static __device__ __forceinline__ void gload16(const void* g, void* l) {
    __builtin_amdgcn_global_load_lds(
        (const __attribute__((address_space(1))) void*)g,
        (__attribute__((address_space(3))) void*)l,
        16, 0, 0);
}

static __device__ __forceinline__ unsigned short f2bf(float f) {
    unsigned int u = __float_as_uint(f);
    u += 0x7fffu + ((u >> 16) & 1u);
    return (unsigned short)(u >> 16);
}

// ---- f32 -> bf16 conversion: X, written with padded row stride PLD ----
__global__ __launch_bounds__(256)
void cvt_x(const float* __restrict__ src, unsigned short* __restrict__ dst, long n)
{
    const long stride = (long)gridDim.x * blockDim.x;
    for (long i = (long)blockIdx.x * blockDim.x + threadIdx.x; i * 4 < n; i += stride) {
        const long o   = i * 4;
        const long row = o >> 11;          // H_DIM = 2048
        const long col = o & 2047;
        const float4 v = *(const float4*)(src + o);
        ushort4 ov;
        ov.x = f2bf(v.x); ov.y = f2bf(v.y); ov.z = f2bf(v.z); ov.w = f2bf(v.w);
        *(ushort4*)(dst + row * PLD + col) = ov;
    }
}

// ---- f32 -> bf16 weight conversion.
// W1/W2 interleaved into W12[11264 x PLD]:
//   W1 row r -> R = (r>>7)*256 + ((r&127)>>5)*64 + (r&31)
//   W2 row r -> R = same + 32        (round-6/7 verified mapping)
// W3 converted linearly (stride 5632 elems, already non-pow2).
__global__ __launch_bounds__(256)
void cvt_w(const float* __restrict__ w1, const float* __restrict__ w2,
           const float* __restrict__ w3, const int* __restrict__ eidx,
           unsigned short* __restrict__ W12, unsigned short* __restrict__ W3b)
{
    const long seg = (long)F_DIM * H_DIM;
    const long e   = (long)(*eidx);
    const long nchunks = 3 * seg / 4;
    const long stride = (long)gridDim.x * blockDim.x;
    for (long i = (long)blockIdx.x * blockDim.x + threadIdx.x; i < nchunks; i += stride) {
        const long t = i * 4;
        const int  s = (int)(t / seg);
        const long o = t - (long)s * seg;
        const float4 v = *(const float4*)((s == 0 ? w1 : s == 1 ? w2 : w3) + e * seg + o);
        ushort4 ov;
        ov.x = f2bf(v.x); ov.y = f2bf(v.y); ov.z = f2bf(v.z); ov.w = f2bf(v.w);
        if (s == 2) {
            *(ushort4*)(W3b + o) = ov;
        } else {
            const long r   = o >> 11;
            const long col = o & 2047;
            const int  l7  = (int)(r & 127);
            const long R   = (r >> 7) * 256 + (l7 >> 5) * 64 + (l7 & 31)
                           + (s == 1 ? 32 : 0);
            *(ushort4*)(W12 + R * PLD + col) = ov;
        }
    }
}

// ---- helpers for the 256-row / BK=64 8-wave pipelined GEMM ----
static __device__ __forceinline__ void stage_half(const unsigned short* __restrict__ g,
                                                  long grow0, long ldk, long kb,
                                                  unsigned short* l, int t, int i0)
{
    const int r  = t >> 3;
    const int cc = ((t & 7) ^ (r & 7)) << 3;   // inverse-swizzled source column
    #pragma unroll
    for (int i = i0; i < i0 + 2; ++i)
        gload16(g + (grow0 + i * 64 + r) * ldk + kb + cc,
                l + i * 4096 + t * 8);
}

static __device__ __forceinline__ bf16x8 ldsfrag(const unsigned short* base,
                                                 int row, int kk, int q)
{
    return *(const bf16x8*)(base + row * 64 + (((kk * 4 + q) ^ (row & 7)) << 3));
}

#define PHASE_BODY(p, STAGE_STMT)                                              \
    {                                                                          \
        bf16x8 af[2][2];                                                       \
        _Pragma("unroll")                                                      \
        for (int l_ = 0; l_ < 2; ++l_)                                         \
            _Pragma("unroll")                                                  \
            for (int kk = 0; kk < 2; ++kk)                                     \
                af[l_][kk] = ldsfrag(la, wm * 128 + (p) * 32 + l_ * 16 + lr, kk, q); \
        STAGE_STMT;                                                            \
        __builtin_amdgcn_s_barrier();                                          \
        __builtin_amdgcn_s_setprio(1);                                         \
        _Pragma("unroll")                                                      \
        for (int l_ = 0; l_ < 2; ++l_)                                         \
            _Pragma("unroll")                                                  \
            for (int ni = 0; ni < 4; ++ni)                                     \
                _Pragma("unroll")                                              \
                for (int kk = 0; kk < 2; ++kk)                                 \
                    acc[(p) * 2 + l_][ni] = __builtin_amdgcn_mfma_f32_16x16x32_bf16( \
                        af[l_][kk], bf[ni][kk], acc[(p) * 2 + l_][ni], 0, 0, 0);     \
        __builtin_amdgcn_s_setprio(0);                                         \
        __builtin_amdgcn_s_barrier();                                          \
    }

// ---- FC1: one 256x(128 gate + 128 up) tile per block, K = 2048 (padded LD).
// acc[mi][0..1] = gate, acc[mi][2..3] = up, same columns; terminal epilogue.
__global__ __launch_bounds__(512, 2)
void gemm_fc1(const unsigned short* __restrict__ X,
              const unsigned short* __restrict__ W12,
              unsigned short* __restrict__ Hout)
{
    constexpr int NK = H_DIM / 64;   // 32

    __shared__ __align__(16) unsigned short sAll[4 * 16384];  // 128 KiB

    const int tid  = threadIdx.x;
    const int lane = tid & 63;
    const int wid  = tid >> 6;
    const int wm   = wid >> 2;
    const int wn   = wid & 3;
    const int q    = lane >> 4;
    const int lr   = lane & 15;

    const int bid = blockIdx.x;
    const int x   = bid & 7;
    const int i   = bid >> 3;        // 0..175
    const int bn  = i >> 2;          // 0..43
    const int bm  = x * 4 + (i & 3); // 0..31

    const long arow0 = (long)bm * 256;
    const long brow0 = (long)bn * 256;

    f32x4 acc[8][4] = {};

    stage_half(X,   arow0, PLD, 0,  sAll,          tid, 0);
    stage_half(X,   arow0, PLD, 0,  sAll,          tid, 2);
    stage_half(W12, brow0, PLD, 0,  sAll + 16384,  tid, 0);
    stage_half(W12, brow0, PLD, 0,  sAll + 16384,  tid, 2);
    stage_half(W12, brow0, PLD, 64, sAll + 49152,  tid, 0);
    stage_half(W12, brow0, PLD, 64, sAll + 49152,  tid, 2);

    for (int j = 0; j < NK; ++j) {
        unsigned short* la = sAll + (j & 1) * 32768;
        unsigned short* lb = la + 16384;

        if (j + 1 < NK) {
            unsigned short* na = sAll + ((j + 1) & 1) * 32768;
            stage_half(X, arow0, PLD, (long)(j + 1) * 64, na, tid, 0);
            stage_half(X, arow0, PLD, (long)(j + 1) * 64, na, tid, 2);
            asm volatile("s_waitcnt vmcnt(8)" ::: "memory");  // tile j drained
        } else {
            asm volatile("s_waitcnt vmcnt(0)" ::: "memory");
        }
        __builtin_amdgcn_s_barrier();

        bf16x8 bf[4][2];
        #pragma unroll
        for (int ni = 0; ni < 4; ++ni)
            #pragma unroll
            for (int kk = 0; kk < 2; ++kk)
                bf[ni][kk] = ldsfrag(lb, wn * 64 + ni * 16 + lr, kk, q);

        PHASE_BODY(0, {})
        PHASE_BODY(1, { if (j + 2 < NK) stage_half(W12, brow0, PLD, (long)(j + 2) * 64, lb, tid, 0); })
        PHASE_BODY(2, { if (j + 2 < NK) stage_half(W12, brow0, PLD, (long)(j + 2) * 64, lb, tid, 2); })
        PHASE_BODY(3, {})
    }

    const long orow = (long)bm * 256 + wm * 128;
    const long ocol = (long)bn * 128 + wn * 32;
    #pragma unroll
    for (int mi = 0; mi < 8; ++mi)
        #pragma unroll
        for (int nj = 0; nj < 2; ++nj)
            #pragma unroll
            for (int r = 0; r < 4; ++r) {
                const float g = acc[mi][nj][r];
                const float u = acc[mi][nj + 2][r];
                const float h = __fdividef(g, 1.0f + __expf(-g)) * u;
                Hout[(orow + mi * 16 + q * 4 + r) * (long)F_DIM +
                     (ocol + nj * 16 + lr)] = f2bf(h);
            }
}

// ---- GEMM2: Out = H * W3^T.  H [T,F] bf16, W3 [H,F] bf16, Out [T,H] f32 ----
__global__ __launch_bounds__(512, 2)
void gemm_out(const unsigned short* __restrict__ A,
              const unsigned short* __restrict__ B,
              float* __restrict__ Out)
{
    constexpr int NK  = F_DIM / 64;   // 88
    constexpr int NBN = H_DIM / 256;  // 8

    __shared__ __align__(16) unsigned short sAll[4 * 16384];

    const int tid  = threadIdx.x;
    const int lane = tid & 63;
    const int wid  = tid >> 6;
    const int wm   = wid >> 2;
    const int wn   = wid & 3;
    const int q    = lane >> 4;
    const int lr   = lane & 15;

    const int nwg = gridDim.x;                 // 256
    const int bid = blockIdx.x;
    const int cpx = nwg >> 3;
    const int swz = (bid & 7) * cpx + (bid >> 3);
    const int bm  = swz / NBN;
    const int bn  = swz % NBN;

    const long arow0 = (long)bm * 256;
    const long brow0 = (long)bn * 256;

    f32x4 acc[8][4] = {};

    stage_half(A, arow0, F_DIM, 0,  sAll,          tid, 0);
    stage_half(A, arow0, F_DIM, 0,  sAll,          tid, 2);
    stage_half(B, brow0, F_DIM, 0,  sAll + 16384,  tid, 0);
    stage_half(B, brow0, F_DIM, 0,  sAll + 16384,  tid, 2);
    stage_half(B, brow0, F_DIM, 64, sAll + 49152,  tid, 0);
    stage_half(B, brow0, F_DIM, 64, sAll + 49152,  tid, 2);

    for (int j = 0; j < NK; ++j) {
        unsigned short* la = sAll + (j & 1) * 32768;
        unsigned short* lb = la + 16384;

        if (j + 1 < NK) {
            unsigned short* na = sAll + ((j + 1) & 1) * 32768;
            stage_half(A, arow0, F_DIM, (long)(j + 1) * 64, na, tid, 0);
            stage_half(A, arow0, F_DIM, (long)(j + 1) * 64, na, tid, 2);
            asm volatile("s_waitcnt vmcnt(8)" ::: "memory");
        } else {
            asm volatile("s_waitcnt vmcnt(0)" ::: "memory");
        }
        __builtin_amdgcn_s_barrier();

        bf16x8 bf[4][2];
        #pragma unroll
        for (int ni = 0; ni < 4; ++ni)
            #pragma unroll
            for (int kk = 0; kk < 2; ++kk)
                bf[ni][kk] = ldsfrag(lb, wn * 64 + ni * 16 + lr, kk, q);

        PHASE_BODY(0, {})
        PHASE_BODY(1, { if (j + 2 < NK) stage_half(B, brow0, F_DIM, (long)(j + 2) * 64, lb, tid, 0); })
        PHASE_BODY(2, { if (j + 2 < NK) stage_half(B, brow0, F_DIM, (long)(j + 2) * 64, lb, tid, 2); })
        PHASE_BODY(3, {})
    }

    const long orow = (long)bm * 256 + wm * 128;
    const long ocol = (long)bn * 256 + wn * 64;
    #pragma unroll
    for (int mi = 0; mi < 8; ++mi)
        #pragma unroll
        for (int ni = 0; ni < 4; ++ni)
            #pragma unroll
            for (int r = 0; r < 4; ++r)
                Out[(orow + mi * 16 + q * 4 + r) * (long)H_DIM + (ocol + ni * 16 + lr)]
                    = acc[mi][ni][r];
}

extern "C" void kernel_launch(void* const* d_in, const int* in_sizes, int n_in,
                              void* d_out, int out_size, void* d_ws, size_t ws_size,
                              hipStream_t stream)
{
    const int*   eidx = (const int*)d_in[0];
    const float* x    = (const float*)d_in[1];
    const float* w1   = (const float*)d_in[2];
    const float* w2   = (const float*)d_in[3];
    const float* w3   = (const float*)d_in[4];
    float* out = (float*)d_out;

    const size_t SZ_XP  = (size_t)T_DIM * PLD;      // padded X
    const size_t SZ_W12 = (size_t)(2 * F_DIM) * PLD;// padded interleaved W1/W2
    const size_t SZ_W3  = (size_t)H_DIM * F_DIM;
    const size_t SZ_H   = (size_t)T_DIM * F_DIM;

    unsigned short* Xb  = (unsigned short*)d_ws;
    unsigned short* W12 = Xb  + SZ_XP;
    unsigned short* W3b = W12 + SZ_W12;
    unsigned short* Hb  = W3b + SZ_W3;
    (void)SZ_H; (void)ws_size;

    cvt_x<<<2048, 256, 0, stream>>>(x, Xb, (long)T_DIM * H_DIM);
    cvt_w<<<2048, 256, 0, stream>>>(w1, w2, w3, eidx, W12, W3b);

    gemm_fc1<<<(T_DIM / 256) * (F_DIM / 128), 512, 0, stream>>>(Xb, W12, Hb);
    gemm_out<<<(T_DIM / 256) * (H_DIM / 256), 512, 0, stream>>>(Hb, W3b, out);
}